// Round 1
// 273.780 us; speedup vs baseline: 1.1184x; 1.1184x over previous
//
#include <hip/hip_runtime.h>

#define NN 50000
#define NE 800000
#define HID 256
#define HALF 128
#define CAP 48                    // bucket capacity; P(Poisson(16) >= 48) ~ 1e-9
#define MT ((NN + 63) / 64)       // 782 gemm m-tiles
#define MLPB (NE / 256)           // 3125 edge-mlp blocks

typedef __attribute__((ext_vector_type(8))) short short8;   // bf16x8 frag
typedef __attribute__((ext_vector_type(4))) float floatx4;  // fp32 acc frag

#define QSCALE 5.9604644775390625e-8f   // 2^-24 fixed-point weight scale

// fp32 -> bf16 round-nearest-even (finite inputs)
__device__ inline unsigned short f2b(float f) {
    unsigned int u = __float_as_uint(f);
    return (unsigned short)((u + 0x7FFFu + ((u >> 16) & 1u)) >> 16);
}
// bf16 bits -> fp32 (exact)
__device__ inline float b2f(unsigned int u) { return __uint_as_float(u << 16); }

// ---- prep: zero qs||cnt (contiguous 400000 B) + Wt[n][k] = bf16(Wc[k][n]) --
__global__ __launch_bounds__(256) void k_prep(const float* __restrict__ Wc,
                                              unsigned short* __restrict__ Wt,
                                              uint4* __restrict__ zb) {
    int t = blockIdx.x * 256 + threadIdx.x;     // 65536 threads
    if (t < 25000) zb[t] = make_uint4(0u, 0u, 0u, 0u);
    int n = t >> 8, k = t & 255;
    Wt[n * 256 + k] = f2b(Wc[k * 256 + n]);
}

// ---- fused: blocks [0,MT) = single-barrier GEMM, [MT,MT+MLPB) = edge MLP ---
__global__ __launch_bounds__(256) void k_mlp_gemm(
    const float* __restrict__ A, const unsigned short* __restrict__ Wt,
    unsigned short* __restrict__ xh,
    const float* __restrict__ ea, const int* __restrict__ eidx,
    const float* __restrict__ W1, const float* __restrict__ b1,
    const float* __restrict__ W2, const float* __restrict__ b2,
    float* __restrict__ w, unsigned int* __restrict__ qs) {
    __shared__ __align__(16) unsigned char SMEM[40960];
    int tid = threadIdx.x;
    if (blockIdx.x < MT) {
        // ---------------- GEMM: xh = bf16(h @ Wc), 64 rows per block --------
        unsigned short* As = (unsigned short*)SMEM;   // [8 chunks][64][40]
        int wave = tid >> 6, lane = tid & 63;
        int mbase = blockIdx.x * 64, nbase = wave * 64;
        int lrow = lane & 15, lg = lane >> 4;
        int srow = tid >> 2, skg = tid & 3;
        int arow = mbase + srow;
        if (arow >= NN) arow = NN - 1;   // clamp: pollutes only unwritten rows
        const float* Ap = A + (size_t)arow * HID + skg * 8;

#define PACKST(c, f0, f1) { uint4 pk;                                   \
        pk.x = (unsigned)f2b(f0.x) | ((unsigned)f2b(f0.y) << 16);       \
        pk.y = (unsigned)f2b(f0.z) | ((unsigned)f2b(f0.w) << 16);       \
        pk.z = (unsigned)f2b(f1.x) | ((unsigned)f2b(f1.y) << 16);       \
        pk.w = (unsigned)f2b(f1.z) | ((unsigned)f2b(f1.w) << 16);       \
        *(uint4*)&As[(c) * 2560 + srow * 40 + skg * 8] = pk; }

        // stage full K=256 (8 chunks of 32), all loads of a group in flight
#pragma unroll
        for (int g = 0; g < 2; ++g) {
            int c0 = g * 4;
            float4 fa0 = *(const float4*)(Ap + (c0 + 0) * 32);
            float4 fb0 = *(const float4*)(Ap + (c0 + 0) * 32 + 4);
            float4 fa1 = *(const float4*)(Ap + (c0 + 1) * 32);
            float4 fb1 = *(const float4*)(Ap + (c0 + 1) * 32 + 4);
            float4 fa2 = *(const float4*)(Ap + (c0 + 2) * 32);
            float4 fb2 = *(const float4*)(Ap + (c0 + 2) * 32 + 4);
            float4 fa3 = *(const float4*)(Ap + (c0 + 3) * 32);
            float4 fb3 = *(const float4*)(Ap + (c0 + 3) * 32 + 4);
            PACKST(c0 + 0, fa0, fb0);
            PACKST(c0 + 1, fa1, fb1);
            PACKST(c0 + 2, fa2, fb2);
            PACKST(c0 + 3, fa3, fb3);
        }
        __syncthreads();   // the ONLY barrier

        floatx4 acc[4][4];
#pragma unroll
        for (int t = 0; t < 4; ++t)
#pragma unroll
            for (int u = 0; u < 4; ++u)
                acc[t][u] = (floatx4){0.f, 0.f, 0.f, 0.f};

#pragma unroll
        for (int c = 0; c < 8; ++c) {
            short8 af[4], bf[4];
#pragma unroll
            for (int t = 0; t < 4; ++t)
                af[t] = *(const short8*)&As[c * 2560 + (t * 16 + lrow) * 40 + lg * 8];
#pragma unroll
            for (int u = 0; u < 4; ++u)
                bf[u] = *(const short8*)&Wt[(nbase + u * 16 + lrow) * 256 + c * 32 + lg * 8];
#pragma unroll
            for (int t = 0; t < 4; ++t)
#pragma unroll
                for (int u = 0; u < 4; ++u)
                    acc[t][u] = __builtin_amdgcn_mfma_f32_16x16x32_bf16(
                        af[t], bf[u], acc[t][u], 0, 0, 0);
        }
        // C/D layout (m89-verified): col = lane&15, row = (lane>>4)*4 + reg
#pragma unroll
        for (int t = 0; t < 4; ++t) {
            int rowb = mbase + t * 16 + lg * 4;
#pragma unroll
            for (int r = 0; r < 4; ++r) {
                int row = rowb + r;
                if (row < NN) {
#pragma unroll
                    for (int u = 0; u < 4; ++u)
                        xh[row * 256 + nbase + u * 16 + lrow] = f2b(acc[t][u][r]);
                }
            }
        }
    } else {
        // ---------------- edge MLP: w[e], qs[col] += q24(w) -----------------
        float4* wp = (float4*)SMEM;            // {W1[0][j],W1[1][j],W1[2][j],b1[j]}
        float* w2s = (float*)(SMEM + 2048);
        if (tid < HALF) {
            wp[tid] = make_float4(W1[tid], W1[HALF + tid], W1[2 * HALF + tid], b1[tid]);
            w2s[tid] = W2[tid];
        }
        __syncthreads();
        int e = (blockIdx.x - MT) * 256 + tid;
        if (e >= NE) return;
        float a0 = ea[3 * e], a1 = ea[3 * e + 1], a2 = ea[3 * e + 2];
        float acc = b2[0];
#pragma unroll 4
        for (int j = 0; j < HALF; ++j) {
            float4 wv = wp[j];                 // LDS broadcast, uniform addr
            float t = fmaf(a0, wv.x, fmaf(a1, wv.y, fmaf(a2, wv.z, wv.w)));
            float s = t * __builtin_amdgcn_rcpf(1.0f + __expf(-t));   // silu
            acc = fmaf(s, w2s[j], acc);
        }
        float wv = __builtin_amdgcn_rcpf(1.0f + __expf(-acc));        // sigmoid
        w[e] = wv;
        int col = eidx[NE + e];
        atomicAdd(&qs[col], __float2uint_rn(wv * 16777216.0f));
    }
}

// ---- fill: slot = cnt[col]++; epk[col*48+slot] = {bf16(norm):16 | row:16} --
__global__ __launch_bounds__(256) void k_fill(
    const int* __restrict__ eidx, const float* __restrict__ w,
    const unsigned int* __restrict__ qs, unsigned int* __restrict__ cnt,
    unsigned int* __restrict__ epk) {
    int e = blockIdx.x * 256 + threadIdx.x;
    if (e >= NE) return;
    int row = eidx[e];
    int col = eidx[NE + e];
    unsigned slot = atomicAdd(&cnt[col], 1u);
    if (slot < CAP) {
        float dr = fmaf((float)qs[row], QSCALE, 1.0f);
        float dc = fmaf((float)qs[col], QSCALE, 1.0f);
        float nm = w[e] * rsqrtf(dr * dc);     // dinv[row]*w*dinv[col]
        epk[col * CAP + slot] = (unsigned)row | ((unsigned)f2b(nm) << 16);
    }
}

// ---- aggregate: wave per node, 8-deep gather batches, prefetched records ---
__global__ __launch_bounds__(256) void k_aggregate(
    const unsigned short* __restrict__ xh, const unsigned int* __restrict__ cnt,
    const unsigned int* __restrict__ qs, const unsigned int* __restrict__ epk,
    const float* __restrict__ bc, float* __restrict__ out) {
    int n = blockIdx.x * 4 + (threadIdx.x >> 6);
    int lane = threadIdx.x & 63;
    if (n >= NN) return;
    int c4 = lane * 4;
    int cn = (int)cnt[n];
    if (cn > CAP) cn = CAP;                    // drop-guard clamp
    float d = fmaf((float)qs[n], QSCALE, 1.0f);
    float s = __builtin_amdgcn_rcpf(d);        // self term: dinv^2 = 1/deg
    ushort4 xv = *(const ushort4*)&xh[n * 256 + c4];
    float4 bv = *(const float4*)&bc[c4];
    float ax = fmaf(b2f(xv.x), s, bv.x);
    float ay = fmaf(b2f(xv.y), s, bv.y);
    float az = fmaf(b2f(xv.z), s, bv.z);
    float aw = fmaf(b2f(xv.w), s, bv.w);

    const uint4* bp = (const uint4*)(epk + n * CAP);   // 12 uint4, 16B-aligned
    int nb = (cn + 7) >> 3;                    // batches of 8 records
    uint4 qa = bp[0], qb = bp[1];              // broadcast loads (uniform addr)
    for (int b = 0; b < nb; ++b) {
        int k0 = b * 8;
        int i2 = 2 * b + 2;                    // unconditional clamped prefetch
        if (i2 > 10) i2 = 10;
        uint4 qa2 = bp[i2], qb2 = bp[i2 + 1];
        // predicate tail records to row0/weight0 (cached, x0 in the fma)
        unsigned p0 = (k0 + 0 < cn) ? qa.x : 0u;
        unsigned p1 = (k0 + 1 < cn) ? qa.y : 0u;
        unsigned p2 = (k0 + 2 < cn) ? qa.z : 0u;
        unsigned p3 = (k0 + 3 < cn) ? qa.w : 0u;
        unsigned p4 = (k0 + 4 < cn) ? qb.x : 0u;
        unsigned p5 = (k0 + 5 < cn) ? qb.y : 0u;
        unsigned p6 = (k0 + 6 < cn) ? qb.z : 0u;
        unsigned p7 = (k0 + 7 < cn) ? qb.w : 0u;
        // 8 independent 512B row gathers in flight
        ushort4 v0 = *(const ushort4*)&xh[(p0 & 0xFFFFu) * 256 + c4];
        ushort4 v1 = *(const ushort4*)&xh[(p1 & 0xFFFFu) * 256 + c4];
        ushort4 v2 = *(const ushort4*)&xh[(p2 & 0xFFFFu) * 256 + c4];
        ushort4 v3 = *(const ushort4*)&xh[(p3 & 0xFFFFu) * 256 + c4];
        ushort4 v4 = *(const ushort4*)&xh[(p4 & 0xFFFFu) * 256 + c4];
        ushort4 v5 = *(const ushort4*)&xh[(p5 & 0xFFFFu) * 256 + c4];
        ushort4 v6 = *(const ushort4*)&xh[(p6 & 0xFFFFu) * 256 + c4];
        ushort4 v7 = *(const ushort4*)&xh[(p7 & 0xFFFFu) * 256 + c4];
        float n0 = b2f(p0 >> 16), n1 = b2f(p1 >> 16);
        float n2 = b2f(p2 >> 16), n3 = b2f(p3 >> 16);
        float n4 = b2f(p4 >> 16), n5 = b2f(p5 >> 16);
        float n6 = b2f(p6 >> 16), n7 = b2f(p7 >> 16);
        ax = fmaf(b2f(v0.x), n0, ax); ay = fmaf(b2f(v0.y), n0, ay);
        az = fmaf(b2f(v0.z), n0, az); aw = fmaf(b2f(v0.w), n0, aw);
        ax = fmaf(b2f(v1.x), n1, ax); ay = fmaf(b2f(v1.y), n1, ay);
        az = fmaf(b2f(v1.z), n1, az); aw = fmaf(b2f(v1.w), n1, aw);
        ax = fmaf(b2f(v2.x), n2, ax); ay = fmaf(b2f(v2.y), n2, ay);
        az = fmaf(b2f(v2.z), n2, az); aw = fmaf(b2f(v2.w), n2, aw);
        ax = fmaf(b2f(v3.x), n3, ax); ay = fmaf(b2f(v3.y), n3, ay);
        az = fmaf(b2f(v3.z), n3, az); aw = fmaf(b2f(v3.w), n3, aw);
        ax = fmaf(b2f(v4.x), n4, ax); ay = fmaf(b2f(v4.y), n4, ay);
        az = fmaf(b2f(v4.z), n4, az); aw = fmaf(b2f(v4.w), n4, aw);
        ax = fmaf(b2f(v5.x), n5, ax); ay = fmaf(b2f(v5.y), n5, ay);
        az = fmaf(b2f(v5.z), n5, az); aw = fmaf(b2f(v5.w), n5, aw);
        ax = fmaf(b2f(v6.x), n6, ax); ay = fmaf(b2f(v6.y), n6, ay);
        az = fmaf(b2f(v6.z), n6, az); aw = fmaf(b2f(v6.w), n6, aw);
        ax = fmaf(b2f(v7.x), n7, ax); ay = fmaf(b2f(v7.y), n7, ay);
        az = fmaf(b2f(v7.z), n7, az); aw = fmaf(b2f(v7.w), n7, aw);
        qa = qa2; qb = qb2;
    }
    *(float4*)&out[n * 256 + c4] = make_float4(ax, ay, az, aw);
}

extern "C" void kernel_launch(void* const* d_in, const int* in_sizes, int n_in,
                              void* d_out, int out_size, void* d_ws, size_t ws_size,
                              hipStream_t stream) {
    const float* h   = (const float*)d_in[0];
    const int* eidx  = (const int*)d_in[1];   // [2, NE]: [0]=src(row), [1]=dst(col)
    const float* ea  = (const float*)d_in[2];
    const float* W1  = (const float*)d_in[3];
    const float* b1  = (const float*)d_in[4];
    const float* W2  = (const float*)d_in[5];
    const float* b2  = (const float*)d_in[6];
    const float* Wc  = (const float*)d_in[7];
    const float* bc  = (const float*)d_in[8];
    float* out = (float*)d_out;

    // workspace layout (~38.9 MB), all offsets 16B-aligned; qs||cnt contiguous
    char* p = (char*)d_ws;
    float* w           = (float*)p;          p += (size_t)NE * 4;          // 3.2 MB
    unsigned int* qs   = (unsigned int*)p;   p += (size_t)NN * 4;          // 0.2 MB
    unsigned int* cnt  = (unsigned int*)p;   p += (size_t)NN * 4;          // 0.2 MB
    unsigned int* epk  = (unsigned int*)p;   p += (size_t)NN * CAP * 4;    // 9.6 MB
    unsigned short* xh = (unsigned short*)p; p += (size_t)NN * HID * 2;    // 25.6 MB
    unsigned short* Wt = (unsigned short*)p;                               // 0.13 MB

    k_prep<<<256, 256, 0, stream>>>(Wc, Wt, (uint4*)qs);
    k_mlp_gemm<<<MT + MLPB, 256, 0, stream>>>(h, Wt, xh, ea, eidx,
                                              W1, b1, W2, b2, w, qs);
    k_fill<<<MLPB, 256, 0, stream>>>(eidx, w, qs, cnt, epk);
    k_aggregate<<<(NN + 3) / 4, 256, 0, stream>>>(xh, cnt, qs, epk, bc, out);
}